// Round 6
// baseline (295.604 us; speedup 1.0000x reference)
//
#include <hip/hip_runtime.h>
#include <hip/hip_bf16.h>
#include <hip/hip_cooperative_groups.h>

namespace cg = cooperative_groups;

#define B_ROWS 4096
#define DIM 256
#define NPAIR 6
#define PITCH 4160              // XT row pitch (elems)
#define BK 256                  // K-chunk (elems) staged per iteration
#define KSPLIT 8
#define KCHUNK (B_ROWS / KSPLIT)   // 512 (fallback path)

typedef short bf16x8 __attribute__((ext_vector_type(8)));
typedef float f32x4 __attribute__((ext_vector_type(4)));

__device__ __forceinline__ const float* sel(const float* e0, const float* e1,
                                            const float* e2, const float* e3, int i) {
    return i == 0 ? e0 : (i == 1 ? e1 : (i == 2 ? e2 : e3));
}

// pair p -> (pi, pj): (0,1),(0,2),(0,3),(1,2),(1,3),(2,3)
__device__ __forceinline__ int pair_i(int p) { return p < 3 ? 0 : (p < 5 ? 1 : 2); }
__device__ __forceinline__ int pair_j(int p) { return p < 3 ? p + 1 : (p < 5 ? p - 1 : 3); }

__device__ __forceinline__ unsigned short f32_to_bf16_rne(float f) {
    unsigned int u = __float_as_uint(f);
    unsigned int r = (u + 0x7FFFu + ((u >> 16) & 1u)) >> 16;
    return (unsigned short)r;
}

// Direct global->LDS async copy, 16 B per lane. LDS dest must be linear in
// lane order within each wave (wave-uniform base + lane*16) — m104/m173.
__device__ __forceinline__ void glds16(const void* g, void* l) {
    __builtin_amdgcn_global_load_lds(
        (const __attribute__((address_space(1))) unsigned int*)(g),
        (__attribute__((address_space(3))) unsigned int*)(l), 16, 0, 0);
}

// ============================ FUSED COOPERATIVE KERNEL ============================
// One dispatch: transpose (grid-strided over 1024 tasks) -> grid.sync ->
// v8 gram (R5-verified, byte-identical schedule) -> grid.sync -> block-0
// finalize. 384 blocks x 512 threads; LDS 64 KB => 2 blocks/CU co-residency,
// __launch_bounds__(512,4) caps VGPR at 128 to keep that occupancy.
__global__ __launch_bounds__(512, 4) void fused_kernel(
        const float* __restrict__ e0, const float* __restrict__ e1,
        const float* __restrict__ e2, const float* __restrict__ e3,
        unsigned short* __restrict__ XT, float* __restrict__ sums_p,
        float* __restrict__ part, float* __restrict__ out) {
    __shared__ __align__(16) char smem[65536];
    int blk = blockIdx.x;            // 0..383
    int tid = threadIdx.x;

    // ---------------- Phase 1: transpose + bf16 convert + partial col sums ----
    {
        float (*T)[65] = (float(*)[65])smem;    // 16.6 KB of the 64 KB
        for (int task = blk; task < 1024; task += 384) {
            int rt = task & 63;
            int ct = (task >> 6) & 3;
            int e  = task >> 8;
            const float* X = sel(e0, e1, e2, e3, e);
            unsigned short* XTe = XT + (size_t)e * DIM * PITCH;

            int c4 = (tid & 15) << 2;
            #pragma unroll
            for (int p = 0; p < 2; ++p) {
                int r = (tid >> 4) + 32 * p;
                float4 v = *(const float4*)&X[(size_t)(rt * 64 + r) * DIM + ct * 64 + c4];
                T[c4 + 0][r] = v.x;
                T[c4 + 1][r] = v.y;
                T[c4 + 2][r] = v.z;
                T[c4 + 3][r] = v.w;
            }
            __syncthreads();

            int c = tid >> 3;
            int roff = (tid & 7) * 8;
            bf16x8 outv;
            float s8 = 0.f;
            #pragma unroll
            for (int s = 0; s < 8; ++s) {
                float f = T[c][roff + s];
                outv[s] = (short)f32_to_bf16_rne(f);
                s8 += f;
            }
            *(bf16x8*)&XTe[(size_t)(ct * 64 + c) * PITCH + rt * 64 + roff] = outv;
            s8 += __shfl_down(s8, 4, 8);
            s8 += __shfl_down(s8, 2, 8);
            s8 += __shfl_down(s8, 1, 8);
            if ((tid & 7) == 0)
                sums_p[((size_t)(e * DIM + ct * 64 + c)) * 64 + rt] = s8;
            __syncthreads();             // T reused next task
        }
    }

    __threadfence();                     // XT/sums_p visible device-wide
    cg::this_grid().sync();

    // ---------------- Phase 2: v8 gram (R5-verified schedule) -----------------
    char* base = smem;
    int p = blk >> 6;
    int tile = blk & 63;
    int a0 = (tile >> 3) * 32;
    int b0 = (tile & 7) * 32;
    int pi = pair_i(p), pj = pair_j(p);
    const unsigned short* Xp = XT + (size_t)pi * DIM * PITCH;
    const unsigned short* Yp = XT + (size_t)pj * DIM * PITCH;

    int w = tid >> 6;
    int L = tid & 63;

    int srow = tid >> 5;                       // 0..15
    int soffb = (tid & 31) * 16;               // byte offset in 512-B segment
    int swzb = soffb ^ ((srow & 7) << 4);
    const unsigned short* gA0 = Xp + (size_t)(a0 + srow) * PITCH + (swzb >> 1);
    const unsigned short* gA1 = Xp + (size_t)(a0 + 16 + srow) * PITCH + (swzb >> 1);
    const unsigned short* gB0 = Yp + (size_t)(b0 + srow) * PITCH + (swzb >> 1);
    const unsigned short* gB1 = Yp + (size_t)(b0 + 16 + srow) * PITCH + (swzb >> 1);
    int lp0 = tid * 16;
    int lp1 = 8192 + tid * 16;

    int rA = L & 15;
    int koffb = w * 64 + (L >> 4) * 16;
    int fr0 = rA * 512 + (koffb ^ ((rA & 7) << 4));

    f32x4 acc[2][2] = {};

    glds16(gA0, base + lp0);
    glds16(gA1, base + lp1);
    glds16(gB0, base + 16384 + lp0);
    glds16(gB1, base + 16384 + lp1);
    __syncthreads();

    for (int c = 0; c < 16; ++c) {
        if (c < 15) {
            int cn = (c + 1) * BK;
            char* Ab = base + ((c + 1) & 1) * 32768;
            glds16(gA0 + cn, Ab + lp0);
            glds16(gA1 + cn, Ab + lp1);
            glds16(gB0 + cn, Ab + 16384 + lp0);
            glds16(gB1 + cn, Ab + 16384 + lp1);
        }
        const char* Ar = base + (c & 1) * 32768;
        bf16x8 a0f = *(const bf16x8*)(Ar + fr0);
        bf16x8 a1f = *(const bf16x8*)(Ar + 8192 + fr0);
        bf16x8 b0f = *(const bf16x8*)(Ar + 16384 + fr0);
        bf16x8 b1f = *(const bf16x8*)(Ar + 16384 + 8192 + fr0);
        acc[0][0] = __builtin_amdgcn_mfma_f32_16x16x32_bf16(a0f, b0f, acc[0][0], 0, 0, 0);
        acc[0][1] = __builtin_amdgcn_mfma_f32_16x16x32_bf16(a0f, b1f, acc[0][1], 0, 0, 0);
        acc[1][0] = __builtin_amdgcn_mfma_f32_16x16x32_bf16(a1f, b0f, acc[1][0], 0, 0, 0);
        acc[1][1] = __builtin_amdgcn_mfma_f32_16x16x32_bf16(a1f, b1f, acc[1][1], 0, 0, 0);
        __syncthreads();
    }

    // epilogue (v7/v8 math, overlaid in smem)
    float* red  = (float*)base;
    float* sA   = (float*)(base + 33792);
    float* sB   = (float*)(base + 33920);
    float* wsum = (float*)(base + 34048);

    #pragma unroll
    for (int ti = 0; ti < 2; ++ti)
        #pragma unroll
        for (int tj = 0; tj < 2; ++tj)
            #pragma unroll
            for (int r = 0; r < 4; ++r) {
                int m = ti * 16 + (L >> 4) * 4 + r;
                int n = tj * 16 + (L & 15);
                red[w * 1056 + m * 33 + n] = acc[ti][tj][r];
            }

    {
        int fl = tid >> 4;
        int pr = tid & 15;
        float4 va = *(const float4*)&sums_p[((size_t)(pi * DIM + a0 + fl)) * 64 + pr * 4];
        float4 vb = *(const float4*)&sums_p[((size_t)(pj * DIM + b0 + fl)) * 64 + pr * 4];
        float sa = va.x + va.y + va.z + va.w;
        float sb = vb.x + vb.y + vb.z + vb.w;
        sa += __shfl_down(sa, 8, 16);
        sa += __shfl_down(sa, 4, 16);
        sa += __shfl_down(sa, 2, 16);
        sa += __shfl_down(sa, 1, 16);
        sb += __shfl_down(sb, 8, 16);
        sb += __shfl_down(sb, 4, 16);
        sb += __shfl_down(sb, 2, 16);
        sb += __shfl_down(sb, 1, 16);
        if (pr == 0) { sA[fl] = sa; sB[fl] = sb; }
    }
    __syncthreads();

    const float inv_b = 1.0f / (float)B_ROWS;
    float local = 0.f;
    #pragma unroll
    for (int q = 0; q < 2; ++q) {
        int pos = tid + q * 512;
        int m = pos >> 5, n = pos & 31;
        float s = 0.f;
        #pragma unroll
        for (int ww = 0; ww < 8; ++ww) s += red[ww * 1056 + m * 33 + n];
        float v = s - sA[m] * sB[n] * inv_b;
        local = fmaf(v, v, local);
    }
    #pragma unroll
    for (int off = 32; off > 0; off >>= 1) local += __shfl_down(local, off, 64);
    if (L == 0) wsum[w] = local;
    __syncthreads();
    if (tid == 0) {
        float s = 0.f;
        #pragma unroll
        for (int ww = 0; ww < 8; ++ww) s += wsum[ww];
        part[blk] = s;
    }

    __threadfence();                     // part visible device-wide
    cg::this_grid().sync();

    // ---------------- Phase 3: finalize in block 0 ----------------------------
    if (blk == 0) {
        float local3 = (tid < NPAIR * 64) ? part[tid] : 0.f;
        #pragma unroll
        for (int off = 32; off > 0; off >>= 1) local3 += __shfl_down(local3, off, 64);
        float* ws2 = (float*)base;       // smem free again
        __syncthreads();
        if ((tid & 63) == 0) ws2[tid >> 6] = local3;
        __syncthreads();
        if (tid == 0) {
            float s = 0.f;
            #pragma unroll
            for (int ww = 0; ww < 8; ++ww) s += ws2[ww];
            const float scale = 0.1f / (6.0f * 4095.0f * 4095.0f);
            out[0] = s * scale;
        }
    }
}

// ============================ 3-DISPATCH VERIFIED PATH (R5) ============================

__global__ __launch_bounds__(256) void transpose_bf16_kernel(
        const float* __restrict__ e0, const float* __restrict__ e1,
        const float* __restrict__ e2, const float* __restrict__ e3,
        unsigned short* __restrict__ XT, float* __restrict__ sums_p) {
    int rt = blockIdx.x;   // 0..63
    int ct = blockIdx.y;   // 0..3
    int e  = blockIdx.z;   // 0..3
    const float* X = sel(e0, e1, e2, e3, e);
    unsigned short* XTe = XT + (size_t)e * DIM * PITCH;

    __shared__ float T[64][65];

    int t = threadIdx.x;
    int c4 = (t & 15) << 2;
    #pragma unroll
    for (int p = 0; p < 4; ++p) {
        int r = (t >> 4) + 16 * p;
        float4 v = *(const float4*)&X[(size_t)(rt * 64 + r) * DIM + ct * 64 + c4];
        T[c4 + 0][r] = v.x;
        T[c4 + 1][r] = v.y;
        T[c4 + 2][r] = v.z;
        T[c4 + 3][r] = v.w;
    }
    __syncthreads();

    #pragma unroll
    for (int p = 0; p < 2; ++p) {
        int id = 256 * p + t;
        int c = id >> 3;
        int roff = (id & 7) * 8;
        bf16x8 outv;
        float s8 = 0.f;
        #pragma unroll
        for (int s = 0; s < 8; ++s) {
            float f = T[c][roff + s];
            outv[s] = (short)f32_to_bf16_rne(f);
            s8 += f;
        }
        *(bf16x8*)&XTe[(size_t)(ct * 64 + c) * PITCH + rt * 64 + roff] = outv;
        s8 += __shfl_down(s8, 4, 8);
        s8 += __shfl_down(s8, 2, 8);
        s8 += __shfl_down(s8, 1, 8);
        if ((id & 7) == 0)
            sums_p[((size_t)(e * DIM + ct * 64 + c)) * 64 + rt] = s8;
    }
}

__global__ __launch_bounds__(512) void gram_v8_kernel(
        const unsigned short* __restrict__ XT, const float* __restrict__ sums_p,
        float* __restrict__ part) {
    __shared__ __align__(16) unsigned short smem[2 * 64 * 256];
    char* base = (char*)smem;

    int blk = blockIdx.x;            // 0..383
    int p = blk >> 6;
    int tile = blk & 63;
    int a0 = (tile >> 3) * 32;
    int b0 = (tile & 7) * 32;
    int pi = pair_i(p), pj = pair_j(p);
    const unsigned short* Xp = XT + (size_t)pi * DIM * PITCH;
    const unsigned short* Yp = XT + (size_t)pj * DIM * PITCH;

    int tid = threadIdx.x;
    int w = tid >> 6;
    int L = tid & 63;

    int srow = tid >> 5;
    int soffb = (tid & 31) * 16;
    int swzb = soffb ^ ((srow & 7) << 4);
    const unsigned short* gA0 = Xp + (size_t)(a0 + srow) * PITCH + (swzb >> 1);
    const unsigned short* gA1 = Xp + (size_t)(a0 + 16 + srow) * PITCH + (swzb >> 1);
    const unsigned short* gB0 = Yp + (size_t)(b0 + srow) * PITCH + (swzb >> 1);
    const unsigned short* gB1 = Yp + (size_t)(b0 + 16 + srow) * PITCH + (swzb >> 1);
    int lp0 = tid * 16;
    int lp1 = 8192 + tid * 16;

    int rA = L & 15;
    int koffb = w * 64 + (L >> 4) * 16;
    int fr0 = rA * 512 + (koffb ^ ((rA & 7) << 4));

    f32x4 acc[2][2] = {};

    glds16(gA0, base + lp0);
    glds16(gA1, base + lp1);
    glds16(gB0, base + 16384 + lp0);
    glds16(gB1, base + 16384 + lp1);
    __syncthreads();

    for (int c = 0; c < 16; ++c) {
        if (c < 15) {
            int cn = (c + 1) * BK;
            char* Ab = base + ((c + 1) & 1) * 32768;
            glds16(gA0 + cn, Ab + lp0);
            glds16(gA1 + cn, Ab + lp1);
            glds16(gB0 + cn, Ab + 16384 + lp0);
            glds16(gB1 + cn, Ab + 16384 + lp1);
        }
        const char* Ar = base + (c & 1) * 32768;
        bf16x8 a0f = *(const bf16x8*)(Ar + fr0);
        bf16x8 a1f = *(const bf16x8*)(Ar + 8192 + fr0);
        bf16x8 b0f = *(const bf16x8*)(Ar + 16384 + fr0);
        bf16x8 b1f = *(const bf16x8*)(Ar + 16384 + 8192 + fr0);
        acc[0][0] = __builtin_amdgcn_mfma_f32_16x16x32_bf16(a0f, b0f, acc[0][0], 0, 0, 0);
        acc[0][1] = __builtin_amdgcn_mfma_f32_16x16x32_bf16(a0f, b1f, acc[0][1], 0, 0, 0);
        acc[1][0] = __builtin_amdgcn_mfma_f32_16x16x32_bf16(a1f, b0f, acc[1][0], 0, 0, 0);
        acc[1][1] = __builtin_amdgcn_mfma_f32_16x16x32_bf16(a1f, b1f, acc[1][1], 0, 0, 0);
        __syncthreads();
    }

    float* red  = (float*)base;
    float* sA   = (float*)(base + 33792);
    float* sB   = (float*)(base + 33920);
    float* wsum = (float*)(base + 34048);

    #pragma unroll
    for (int ti = 0; ti < 2; ++ti)
        #pragma unroll
        for (int tj = 0; tj < 2; ++tj)
            #pragma unroll
            for (int r = 0; r < 4; ++r) {
                int m = ti * 16 + (L >> 4) * 4 + r;
                int n = tj * 16 + (L & 15);
                red[w * 1056 + m * 33 + n] = acc[ti][tj][r];
            }

    {
        int fl = tid >> 4;
        int pr = tid & 15;
        float4 va = *(const float4*)&sums_p[((size_t)(pi * DIM + a0 + fl)) * 64 + pr * 4];
        float4 vb = *(const float4*)&sums_p[((size_t)(pj * DIM + b0 + fl)) * 64 + pr * 4];
        float sa = va.x + va.y + va.z + va.w;
        float sb = vb.x + vb.y + vb.z + vb.w;
        sa += __shfl_down(sa, 8, 16);
        sa += __shfl_down(sa, 4, 16);
        sa += __shfl_down(sa, 2, 16);
        sa += __shfl_down(sa, 1, 16);
        sb += __shfl_down(sb, 8, 16);
        sb += __shfl_down(sb, 4, 16);
        sb += __shfl_down(sb, 2, 16);
        sb += __shfl_down(sb, 1, 16);
        if (pr == 0) { sA[fl] = sa; sB[fl] = sb; }
    }
    __syncthreads();

    const float inv_b = 1.0f / (float)B_ROWS;
    float local = 0.f;
    #pragma unroll
    for (int q = 0; q < 2; ++q) {
        int pos = tid + q * 512;
        int m = pos >> 5, n = pos & 31;
        float s = 0.f;
        #pragma unroll
        for (int ww = 0; ww < 8; ++ww) s += red[ww * 1056 + m * 33 + n];
        float v = s - sA[m] * sB[n] * inv_b;
        local = fmaf(v, v, local);
    }
    #pragma unroll
    for (int off = 32; off > 0; off >>= 1) local += __shfl_down(local, off, 64);
    if (L == 0) wsum[w] = local;
    __syncthreads();
    if (tid == 0) {
        float s = 0.f;
        #pragma unroll
        for (int ww = 0; ww < 8; ++ww) s += wsum[ww];
        part[blk] = s;
    }
}

__global__ __launch_bounds__(512) void finalize384_kernel(
        const float* __restrict__ part, float* __restrict__ out) {
    int t = threadIdx.x;
    float local = (t < NPAIR * 64) ? part[t] : 0.f;
    #pragma unroll
    for (int off = 32; off > 0; off >>= 1) local += __shfl_down(local, off, 64);
    __shared__ float ws2[8];
    if ((t & 63) == 0) ws2[t >> 6] = local;
    __syncthreads();
    if (t == 0) {
        float s = 0.f;
        #pragma unroll
        for (int ww = 0; ww < 8; ++ww) s += ws2[ww];
        const float scale = 0.1f / (6.0f * 4095.0f * 4095.0f);
        out[0] = s * scale;
    }
}

__global__ void finalize_kernel(const float* __restrict__ acc, float* __restrict__ out) {
    if (threadIdx.x == 0) {
        const float scale = 0.1f / (6.0f * 4095.0f * 4095.0f);
        out[0] = acc[0] * scale;
    }
}

// ============================ FALLBACK (R3 passing fp32 path) ============================

__global__ void col_sums_kernel(const float* __restrict__ e0, const float* __restrict__ e1,
                                const float* __restrict__ e2, const float* __restrict__ e3,
                                float* __restrict__ sums) {
    int e = blockIdx.y;
    const float* X = sel(e0, e1, e2, e3, e);
    int c = threadIdx.x;
    int r0 = blockIdx.x * 128;
    float s = 0.f;
    #pragma unroll 4
    for (int r = r0; r < r0 + 128; ++r) s += X[r * DIM + c];
    atomicAdd(&sums[e * DIM + c], s);
}

__global__ __launch_bounds__(256) void gram_kernel(
        const float* __restrict__ e0, const float* __restrict__ e1,
        const float* __restrict__ e2, const float* __restrict__ e3,
        float* __restrict__ G) {
    int kc = blockIdx.x;
    int tile = blockIdx.y;
    int p = blockIdx.z;
    const float* X = sel(e0, e1, e2, e3, pair_i(p));
    const float* Y = sel(e0, e1, e2, e3, pair_j(p));
    int a0 = (tile >> 2) * 64;
    int b0 = (tile & 3) * 64;
    int k0 = kc * KCHUNK;
    __shared__ float As[16][64];
    __shared__ float Bs[16][64];
    int lid = threadIdx.x;
    int lr = lid >> 4;
    int lc = (lid & 15) << 2;
    int ty = lid >> 4;
    int tx = lid & 15;
    float acc[4][4] = {};
    for (int ks = 0; ks < KCHUNK; ks += 16) {
        int row = k0 + ks + lr;
        float4 av = *(const float4*)&X[row * DIM + a0 + lc];
        float4 bv = *(const float4*)&Y[row * DIM + b0 + lc];
        __syncthreads();
        *(float4*)&As[lr][lc] = av;
        *(float4*)&Bs[lr][lc] = bv;
        __syncthreads();
        #pragma unroll
        for (int k = 0; k < 16; ++k) {
            float a[4], b[4];
            *(float4*)a = *(const float4*)&As[k][ty * 4];
            *(float4*)b = *(const float4*)&Bs[k][tx * 4];
            #pragma unroll
            for (int i = 0; i < 4; ++i)
                #pragma unroll
                for (int j = 0; j < 4; ++j)
                    acc[i][j] = fmaf(a[i], b[j], acc[i][j]);
        }
    }
    float* Gp = G + p * (DIM * DIM);
    #pragma unroll
    for (int i = 0; i < 4; ++i)
        #pragma unroll
        for (int j = 0; j < 4; ++j)
            atomicAdd(&Gp[(a0 + ty * 4 + i) * DIM + (b0 + tx * 4 + j)], acc[i][j]);
}

__global__ void reduce_kernel(const float* __restrict__ G, const float* __restrict__ sums,
                              float* __restrict__ acc) {
    float local = 0.f;
    const int total = NPAIR * DIM * DIM;
    for (int idx = blockIdx.x * blockDim.x + threadIdx.x; idx < total;
         idx += gridDim.x * blockDim.x) {
        int p = idx >> 16;
        int ab = idx & 65535;
        int a = ab >> 8;
        int b = ab & 255;
        float v = G[idx] - sums[pair_i(p) * DIM + a] * sums[pair_j(p) * DIM + b] * (1.0f / (float)B_ROWS);
        local = fmaf(v, v, local);
    }
    #pragma unroll
    for (int off = 32; off > 0; off >>= 1) local += __shfl_down(local, off, 64);
    __shared__ float wsum[4];
    if ((threadIdx.x & 63) == 0) wsum[threadIdx.x >> 6] = local;
    __syncthreads();
    if (threadIdx.x == 0) {
        float s = wsum[0] + wsum[1] + wsum[2] + wsum[3];
        atomicAdd(acc, s);
    }
}

// ============================ LAUNCH ============================

extern "C" void kernel_launch(void* const* d_in, const int* in_sizes, int n_in,
                              void* d_out, int out_size, void* d_ws, size_t ws_size,
                              hipStream_t stream) {
    const float* e0 = (const float*)d_in[0];
    const float* e1 = (const float*)d_in[1];
    const float* e2 = (const float*)d_in[2];
    const float* e3 = (const float*)d_in[3];

    // Main-path workspace layout (no zero-init required anywhere):
    //   sums_p : 4*256*64 f32 = 256 KB   @ 0
    //   part   : 384 f32                 @ 262144
    //   XT     : 4*256*4160 bf16 ~8.5 MB @ 266240
    size_t need = 266240 + (size_t)4 * DIM * PITCH * sizeof(unsigned short);

    if (ws_size >= need) {
        float* sums_p = (float*)d_ws;
        float* part = (float*)((char*)d_ws + 262144);
        unsigned short* XT = (unsigned short*)((char*)d_ws + 266240);
        float* outp = (float*)d_out;

        void* args[] = {(void*)&e0, (void*)&e1, (void*)&e2, (void*)&e3,
                        (void*)&XT, (void*)&sums_p, (void*)&part, (void*)&outp};
        hipError_t err = hipLaunchCooperativeKernel(
            (const void*)fused_kernel, dim3(NPAIR * 64), dim3(512), args, 0, stream);
        if (err != hipSuccess) {
            // R5-verified 3-dispatch path
            transpose_bf16_kernel<<<dim3(64, 4, 4), 256, 0, stream>>>(e0, e1, e2, e3, XT, sums_p);
            gram_v8_kernel<<<NPAIR * 64, 512, 0, stream>>>(XT, sums_p, part);
            finalize384_kernel<<<1, 512, 0, stream>>>(part, (float*)d_out);
        }
    } else {
        // fallback: fp32 vector path (passed in R3)
        float* sums = (float*)d_ws;                            // 4*256 f32 = 4 KB
        float* acc  = (float*)((char*)d_ws + 4096);            // 1 f32
        float* G = (float*)((char*)d_ws + 8192);
        size_t zbytes = 8192 + (size_t)NPAIR * DIM * DIM * sizeof(float);
        hipMemsetAsync(d_ws, 0, zbytes, stream);
        col_sums_kernel<<<dim3(32, 4), 256, 0, stream>>>(e0, e1, e2, e3, sums);
        gram_kernel<<<dim3(KSPLIT, 16, NPAIR), 256, 0, stream>>>(e0, e1, e2, e3, G);
        reduce_kernel<<<384, 256, 0, stream>>>(G, sums, acc);
        finalize_kernel<<<1, 64, 0, stream>>>(acc, (float*)d_out);
    }
}

// Round 7
// 94.042 us; speedup vs baseline: 3.1433x; 3.1433x over previous
//
#include <hip/hip_runtime.h>
#include <hip/hip_bf16.h>

#define B_ROWS 4096
#define DIM 256
#define NPAIR 6
#define PITCH 4160              // XT row pitch (elems)
#define BK 256                  // K-chunk (elems) staged per iteration
#define KSPLIT 8
#define KCHUNK (B_ROWS / KSPLIT)   // 512 (fallback path)

typedef short bf16x8 __attribute__((ext_vector_type(8)));
typedef float f32x4 __attribute__((ext_vector_type(4)));

__device__ __forceinline__ const float* sel(const float* e0, const float* e1,
                                            const float* e2, const float* e3, int i) {
    return i == 0 ? e0 : (i == 1 ? e1 : (i == 2 ? e2 : e3));
}

// pair p -> (pi, pj): (0,1),(0,2),(0,3),(1,2),(1,3),(2,3)
__device__ __forceinline__ int pair_i(int p) { return p < 3 ? 0 : (p < 5 ? 1 : 2); }
__device__ __forceinline__ int pair_j(int p) { return p < 3 ? p + 1 : (p < 5 ? p - 1 : 3); }

__device__ __forceinline__ unsigned short f32_to_bf16_rne(float f) {
    unsigned int u = __float_as_uint(f);
    unsigned int r = (u + 0x7FFFu + ((u >> 16) & 1u)) >> 16;
    return (unsigned short)r;
}

// Direct global->LDS async copy, 16 B per lane. LDS dest must be linear in
// lane order within each wave (wave-uniform base + lane*16) — m104/m173.
__device__ __forceinline__ void glds16(const void* g, void* l) {
    __builtin_amdgcn_global_load_lds(
        (const __attribute__((address_space(1))) unsigned int*)(g),
        (__attribute__((address_space(3))) unsigned int*)(l), 16, 0, 0);
}

// ============================ MFMA PATH (2 dispatches) ============================

// Kernel 1: transpose + convert + per-block partial column sums (R4/R5-verified).
// Additionally: block (0,0,0) zeroes the gram done-counter — this kernel fully
// precedes gram in-stream, so cnt=0 is visible device-wide at gram start
// (no memset dispatch needed; workspace is re-poisoned every iteration).
__global__ __launch_bounds__(256) void transpose_bf16_kernel(
        const float* __restrict__ e0, const float* __restrict__ e1,
        const float* __restrict__ e2, const float* __restrict__ e3,
        unsigned short* __restrict__ XT, float* __restrict__ sums_p,
        unsigned int* __restrict__ cnt) {
    int rt = blockIdx.x;   // 0..63
    int ct = blockIdx.y;   // 0..3
    int e  = blockIdx.z;   // 0..3
    const float* X = sel(e0, e1, e2, e3, e);
    unsigned short* XTe = XT + (size_t)e * DIM * PITCH;

    if (rt == 0 && ct == 0 && e == 0 && threadIdx.x == 0) cnt[0] = 0u;

    __shared__ float T[64][65];

    int t = threadIdx.x;
    int c4 = (t & 15) << 2;
    #pragma unroll
    for (int p = 0; p < 4; ++p) {
        int r = (t >> 4) + 16 * p;
        float4 v = *(const float4*)&X[(size_t)(rt * 64 + r) * DIM + ct * 64 + c4];
        T[c4 + 0][r] = v.x;
        T[c4 + 1][r] = v.y;
        T[c4 + 2][r] = v.z;
        T[c4 + 3][r] = v.w;
    }
    __syncthreads();

    #pragma unroll
    for (int p = 0; p < 2; ++p) {
        int id = 256 * p + t;
        int c = id >> 3;
        int roff = (id & 7) * 8;
        bf16x8 outv;
        float s8 = 0.f;
        #pragma unroll
        for (int s = 0; s < 8; ++s) {
            float f = T[c][roff + s];
            outv[s] = (short)f32_to_bf16_rne(f);
            s8 += f;
        }
        *(bf16x8*)&XTe[(size_t)(ct * 64 + c) * PITCH + rt * 64 + roff] = outv;
        s8 += __shfl_down(s8, 4, 8);
        s8 += __shfl_down(s8, 2, 8);
        s8 += __shfl_down(s8, 1, 8);
        if ((id & 7) == 0)
            sums_p[((size_t)(e * DIM + ct * 64 + c)) * 64 + rt] = s8;
    }
}

// Kernel 2 (v9): R5-verified v8 gram (glds16 double-buffer, 1 barrier/chunk,
// XOR-swizzled frag reads) + fused finalize via done-counter: each block
// plain-stores part[blk], threadfence, bumps cnt; the last-arriving block
// re-reads all 384 partials (release/acquire via the atomic) and writes the
// scaled scalar. Saves the third dispatch (~2.75 µs per R4 calibration).
__global__ __launch_bounds__(512) void gram_v9_kernel(
        const unsigned short* __restrict__ XT, const float* __restrict__ sums_p,
        float* __restrict__ part, unsigned int* __restrict__ cnt,
        float* __restrict__ out) {
    __shared__ __align__(16) unsigned short smem[2 * 64 * 256];   // 65536 B
    char* base = (char*)smem;

    int blk = blockIdx.x;            // 0..383
    int p = blk >> 6;
    int tile = blk & 63;
    int a0 = (tile >> 3) * 32;
    int b0 = (tile & 7) * 32;
    int pi = pair_i(p), pj = pair_j(p);
    const unsigned short* Xp = XT + (size_t)pi * DIM * PITCH;
    const unsigned short* Yp = XT + (size_t)pj * DIM * PITCH;

    int tid = threadIdx.x;
    int w = tid >> 6;                // wave 0..7 -> k-slice within each chunk
    int L = tid & 63;

    int srow = tid >> 5;                       // 0..15
    int soffb = (tid & 31) * 16;               // byte offset in 512-B segment
    int swzb = soffb ^ ((srow & 7) << 4);      // (16+srow)&7 == srow&7
    const unsigned short* gA0 = Xp + (size_t)(a0 + srow) * PITCH + (swzb >> 1);
    const unsigned short* gA1 = Xp + (size_t)(a0 + 16 + srow) * PITCH + (swzb >> 1);
    const unsigned short* gB0 = Yp + (size_t)(b0 + srow) * PITCH + (swzb >> 1);
    const unsigned short* gB1 = Yp + (size_t)(b0 + 16 + srow) * PITCH + (swzb >> 1);
    int lp0 = tid * 16;
    int lp1 = 8192 + tid * 16;

    int rA = L & 15;
    int koffb = w * 64 + (L >> 4) * 16;
    int fr0 = rA * 512 + (koffb ^ ((rA & 7) << 4));

    f32x4 acc[2][2] = {};

    glds16(gA0, base + lp0);
    glds16(gA1, base + lp1);
    glds16(gB0, base + 16384 + lp0);
    glds16(gB1, base + 16384 + lp1);
    __syncthreads();

    for (int c = 0; c < 16; ++c) {
        if (c < 15) {
            int cn = (c + 1) * BK;
            char* Ab = base + ((c + 1) & 1) * 32768;
            glds16(gA0 + cn, Ab + lp0);
            glds16(gA1 + cn, Ab + lp1);
            glds16(gB0 + cn, Ab + 16384 + lp0);
            glds16(gB1 + cn, Ab + 16384 + lp1);
        }
        const char* Ar = base + (c & 1) * 32768;
        bf16x8 a0f = *(const bf16x8*)(Ar + fr0);
        bf16x8 a1f = *(const bf16x8*)(Ar + 8192 + fr0);
        bf16x8 b0f = *(const bf16x8*)(Ar + 16384 + fr0);
        bf16x8 b1f = *(const bf16x8*)(Ar + 16384 + 8192 + fr0);
        acc[0][0] = __builtin_amdgcn_mfma_f32_16x16x32_bf16(a0f, b0f, acc[0][0], 0, 0, 0);
        acc[0][1] = __builtin_amdgcn_mfma_f32_16x16x32_bf16(a0f, b1f, acc[0][1], 0, 0, 0);
        acc[1][0] = __builtin_amdgcn_mfma_f32_16x16x32_bf16(a1f, b0f, acc[1][0], 0, 0, 0);
        acc[1][1] = __builtin_amdgcn_mfma_f32_16x16x32_bf16(a1f, b1f, acc[1][1], 0, 0, 0);
        __syncthreads();
    }

    float* red  = (float*)base;
    float* sA   = (float*)(base + 33792);
    float* sB   = (float*)(base + 33920);
    float* wsum = (float*)(base + 34048);

    // C/D layout: col = lane&15, row = (lane>>4)*4 + reg   [measured m89/m91]
    #pragma unroll
    for (int ti = 0; ti < 2; ++ti)
        #pragma unroll
        for (int tj = 0; tj < 2; ++tj)
            #pragma unroll
            for (int r = 0; r < 4; ++r) {
                int m = ti * 16 + (L >> 4) * 4 + r;
                int n = tj * 16 + (L & 15);
                red[w * 1056 + m * 33 + n] = acc[ti][tj][r];
            }

    {
        int fl = tid >> 4;
        int pr = tid & 15;
        float4 va = *(const float4*)&sums_p[((size_t)(pi * DIM + a0 + fl)) * 64 + pr * 4];
        float4 vb = *(const float4*)&sums_p[((size_t)(pj * DIM + b0 + fl)) * 64 + pr * 4];
        float sa = va.x + va.y + va.z + va.w;
        float sb = vb.x + vb.y + vb.z + vb.w;
        sa += __shfl_down(sa, 8, 16);
        sa += __shfl_down(sa, 4, 16);
        sa += __shfl_down(sa, 2, 16);
        sa += __shfl_down(sa, 1, 16);
        sb += __shfl_down(sb, 8, 16);
        sb += __shfl_down(sb, 4, 16);
        sb += __shfl_down(sb, 2, 16);
        sb += __shfl_down(sb, 1, 16);
        if (pr == 0) { sA[fl] = sa; sB[fl] = sb; }
    }
    __syncthreads();

    const float inv_b = 1.0f / (float)B_ROWS;
    float local = 0.f;
    #pragma unroll
    for (int q = 0; q < 2; ++q) {
        int pos = tid + q * 512;
        int m = pos >> 5, n = pos & 31;
        float s = 0.f;
        #pragma unroll
        for (int ww = 0; ww < 8; ++ww) s += red[ww * 1056 + m * 33 + n];
        float v = s - sA[m] * sB[n] * inv_b;
        local = fmaf(v, v, local);
    }
    #pragma unroll
    for (int off = 32; off > 0; off >>= 1) local += __shfl_down(local, off, 64);
    if (L == 0) wsum[w] = local;
    __syncthreads();

    // fused finalize: last-arriving block reduces all 384 partials
    __shared__ unsigned int lastflag;
    if (tid == 0) {
        float s = 0.f;
        #pragma unroll
        for (int ww = 0; ww < 8; ++ww) s += wsum[ww];
        part[blk] = s;                   // plain store — no atomic, no zero-init
        __threadfence();                 // release: part[blk] before cnt bump
        unsigned int old = atomicAdd(cnt, 1u);
        lastflag = (old == (unsigned int)(gridDim.x - 1)) ? 1u : 0u;
    }
    __syncthreads();
    if (lastflag) {
        __threadfence();                 // acquire: all part[] stores visible
        float l3 = (tid < NPAIR * 64) ? part[tid] : 0.f;
        #pragma unroll
        for (int off = 32; off > 0; off >>= 1) l3 += __shfl_down(l3, off, 64);
        float* ws2 = (float*)base;
        __syncthreads();
        if (L == 0) ws2[w] = l3;
        __syncthreads();
        if (tid == 0) {
            float s = 0.f;
            #pragma unroll
            for (int ww = 0; ww < 8; ++ww) s += ws2[ww];
            const float scale = 0.1f / (6.0f * 4095.0f * 4095.0f);
            out[0] = s * scale;
        }
    }
}

// Fallback-path finalize (scalar accumulator).
__global__ void finalize_kernel(const float* __restrict__ acc, float* __restrict__ out) {
    if (threadIdx.x == 0) {
        const float scale = 0.1f / (6.0f * 4095.0f * 4095.0f);
        out[0] = acc[0] * scale;
    }
}

// ============================ FALLBACK (R3 passing fp32 path) ============================

__global__ void col_sums_kernel(const float* __restrict__ e0, const float* __restrict__ e1,
                                const float* __restrict__ e2, const float* __restrict__ e3,
                                float* __restrict__ sums) {
    int e = blockIdx.y;
    const float* X = sel(e0, e1, e2, e3, e);
    int c = threadIdx.x;
    int r0 = blockIdx.x * 128;
    float s = 0.f;
    #pragma unroll 4
    for (int r = r0; r < r0 + 128; ++r) s += X[r * DIM + c];
    atomicAdd(&sums[e * DIM + c], s);
}

__global__ __launch_bounds__(256) void gram_kernel(
        const float* __restrict__ e0, const float* __restrict__ e1,
        const float* __restrict__ e2, const float* __restrict__ e3,
        float* __restrict__ G) {
    int kc = blockIdx.x;
    int tile = blockIdx.y;
    int p = blockIdx.z;
    const float* X = sel(e0, e1, e2, e3, pair_i(p));
    const float* Y = sel(e0, e1, e2, e3, pair_j(p));
    int a0 = (tile >> 2) * 64;
    int b0 = (tile & 3) * 64;
    int k0 = kc * KCHUNK;
    __shared__ float As[16][64];
    __shared__ float Bs[16][64];
    int lid = threadIdx.x;
    int lr = lid >> 4;
    int lc = (lid & 15) << 2;
    int ty = lid >> 4;
    int tx = lid & 15;
    float acc[4][4] = {};
    for (int ks = 0; ks < KCHUNK; ks += 16) {
        int row = k0 + ks + lr;
        float4 av = *(const float4*)&X[row * DIM + a0 + lc];
        float4 bv = *(const float4*)&Y[row * DIM + b0 + lc];
        __syncthreads();
        *(float4*)&As[lr][lc] = av;
        *(float4*)&Bs[lr][lc] = bv;
        __syncthreads();
        #pragma unroll
        for (int k = 0; k < 16; ++k) {
            float a[4], b[4];
            *(float4*)a = *(const float4*)&As[k][ty * 4];
            *(float4*)b = *(const float4*)&Bs[k][tx * 4];
            #pragma unroll
            for (int i = 0; i < 4; ++i)
                #pragma unroll
                for (int j = 0; j < 4; ++j)
                    acc[i][j] = fmaf(a[i], b[j], acc[i][j]);
        }
    }
    float* Gp = G + p * (DIM * DIM);
    #pragma unroll
    for (int i = 0; i < 4; ++i)
        #pragma unroll
        for (int j = 0; j < 4; ++j)
            atomicAdd(&Gp[(a0 + ty * 4 + i) * DIM + (b0 + tx * 4 + j)], acc[i][j]);
}

__global__ void reduce_kernel(const float* __restrict__ G, const float* __restrict__ sums,
                              float* __restrict__ acc) {
    float local = 0.f;
    const int total = NPAIR * DIM * DIM;
    for (int idx = blockIdx.x * blockDim.x + threadIdx.x; idx < total;
         idx += gridDim.x * blockDim.x) {
        int p = idx >> 16;
        int ab = idx & 65535;
        int a = ab >> 8;
        int b = ab & 255;
        float v = G[idx] - sums[pair_i(p) * DIM + a] * sums[pair_j(p) * DIM + b] * (1.0f / (float)B_ROWS);
        local = fmaf(v, v, local);
    }
    #pragma unroll
    for (int off = 32; off > 0; off >>= 1) local += __shfl_down(local, off, 64);
    __shared__ float wsum[4];
    if ((threadIdx.x & 63) == 0) wsum[threadIdx.x >> 6] = local;
    __syncthreads();
    if (threadIdx.x == 0) {
        float s = wsum[0] + wsum[1] + wsum[2] + wsum[3];
        atomicAdd(acc, s);
    }
}

// ============================ LAUNCH ============================

extern "C" void kernel_launch(void* const* d_in, const int* in_sizes, int n_in,
                              void* d_out, int out_size, void* d_ws, size_t ws_size,
                              hipStream_t stream) {
    const float* e0 = (const float*)d_in[0];
    const float* e1 = (const float*)d_in[1];
    const float* e2 = (const float*)d_in[2];
    const float* e3 = (const float*)d_in[3];

    // Main-path workspace layout (no zero-init required anywhere):
    //   sums_p : 4*256*64 f32 = 256 KB   @ 0
    //   part   : 384 f32                 @ 262144
    //   cnt    : 1 u32                   @ 264192
    //   XT     : 4*256*4160 bf16 ~8.5 MB @ 266240
    size_t need = 266240 + (size_t)4 * DIM * PITCH * sizeof(unsigned short);

    if (ws_size >= need) {
        float* sums_p = (float*)d_ws;
        float* part = (float*)((char*)d_ws + 262144);
        unsigned int* cnt = (unsigned int*)((char*)d_ws + 264192);
        unsigned short* XT = (unsigned short*)((char*)d_ws + 266240);
        transpose_bf16_kernel<<<dim3(64, 4, 4), 256, 0, stream>>>(e0, e1, e2, e3, XT, sums_p, cnt);
        gram_v9_kernel<<<NPAIR * 64, 512, 0, stream>>>(XT, sums_p, part, cnt, (float*)d_out);
    } else {
        // fallback: fp32 vector path (passed in R3)
        float* sums = (float*)d_ws;                            // 4*256 f32 = 4 KB
        float* acc  = (float*)((char*)d_ws + 4096);            // 1 f32
        float* G = (float*)((char*)d_ws + 8192);
        size_t zbytes = 8192 + (size_t)NPAIR * DIM * DIM * sizeof(float);
        hipMemsetAsync(d_ws, 0, zbytes, stream);
        col_sums_kernel<<<dim3(32, 4), 256, 0, stream>>>(e0, e1, e2, e3, sums);
        gram_kernel<<<dim3(KSPLIT, 16, NPAIR), 256, 0, stream>>>(e0, e1, e2, e3, G);
        reduce_kernel<<<384, 256, 0, stream>>>(G, sums, acc);
        finalize_kernel<<<1, 64, 0, stream>>>(acc, (float*)d_out);
    }
}

// Round 8
// 85.638 us; speedup vs baseline: 3.4518x; 1.0981x over previous
//
#include <hip/hip_runtime.h>
#include <hip/hip_bf16.h>

#define B_ROWS 4096
#define DIM 256
#define NPAIR 6
#define PITCH 4160              // XT row pitch (elems)
#define BK 256                  // K-chunk (elems) staged per iteration
#define KSPLIT 8
#define KCHUNK (B_ROWS / KSPLIT)   // 512 (fallback path)

typedef short bf16x8 __attribute__((ext_vector_type(8)));
typedef float f32x4 __attribute__((ext_vector_type(4)));

__device__ __forceinline__ const float* sel(const float* e0, const float* e1,
                                            const float* e2, const float* e3, int i) {
    return i == 0 ? e0 : (i == 1 ? e1 : (i == 2 ? e2 : e3));
}

// pair p -> (pi, pj): (0,1),(0,2),(0,3),(1,2),(1,3),(2,3)
__device__ __forceinline__ int pair_i(int p) { return p < 3 ? 0 : (p < 5 ? 1 : 2); }
__device__ __forceinline__ int pair_j(int p) { return p < 3 ? p + 1 : (p < 5 ? p - 1 : 3); }

__device__ __forceinline__ unsigned short f32_to_bf16_rne(float f) {
    unsigned int u = __float_as_uint(f);
    unsigned int r = (u + 0x7FFFu + ((u >> 16) & 1u)) >> 16;
    return (unsigned short)r;
}

// Direct global->LDS async copy, 16 B per lane. LDS dest must be linear in
// lane order within each wave (wave-uniform base + lane*16) — m104/m173.
__device__ __forceinline__ void glds16(const void* g, void* l) {
    __builtin_amdgcn_global_load_lds(
        (const __attribute__((address_space(1))) unsigned int*)(g),
        (__attribute__((address_space(3))) unsigned int*)(l), 16, 0, 0);
}

// ============================ MFMA PATH (3 dispatches, R5-verified) ============================

// Kernel 1: transpose + convert + per-block partial column sums (R4/R5-verified).
__global__ __launch_bounds__(256) void transpose_bf16_kernel(
        const float* __restrict__ e0, const float* __restrict__ e1,
        const float* __restrict__ e2, const float* __restrict__ e3,
        unsigned short* __restrict__ XT, float* __restrict__ sums_p) {
    int rt = blockIdx.x;   // 0..63
    int ct = blockIdx.y;   // 0..3
    int e  = blockIdx.z;   // 0..3
    const float* X = sel(e0, e1, e2, e3, e);
    unsigned short* XTe = XT + (size_t)e * DIM * PITCH;

    __shared__ float T[64][65];

    int t = threadIdx.x;
    int c4 = (t & 15) << 2;
    #pragma unroll
    for (int p = 0; p < 4; ++p) {
        int r = (t >> 4) + 16 * p;
        float4 v = *(const float4*)&X[(size_t)(rt * 64 + r) * DIM + ct * 64 + c4];
        T[c4 + 0][r] = v.x;
        T[c4 + 1][r] = v.y;
        T[c4 + 2][r] = v.z;
        T[c4 + 3][r] = v.w;
    }
    __syncthreads();

    #pragma unroll
    for (int p = 0; p < 2; ++p) {
        int id = 256 * p + t;
        int c = id >> 3;
        int roff = (id & 7) * 8;
        bf16x8 outv;
        float s8 = 0.f;
        #pragma unroll
        for (int s = 0; s < 8; ++s) {
            float f = T[c][roff + s];
            outv[s] = (short)f32_to_bf16_rne(f);
            s8 += f;
        }
        *(bf16x8*)&XTe[(size_t)(ct * 64 + c) * PITCH + rt * 64 + roff] = outv;
        s8 += __shfl_down(s8, 4, 8);
        s8 += __shfl_down(s8, 2, 8);
        s8 += __shfl_down(s8, 1, 8);
        if ((id & 7) == 0)
            sums_p[((size_t)(e * DIM + ct * 64 + c)) * 64 + rt] = s8;
    }
}

// Kernel 2 (v10): R5-verified v8 gram + T1 XCD-bijective block swizzle.
// Without swizzle, consecutive blockIdx round-robin across the 8 XCDs, so each
// XCD's resident blocks span all 6 pairs -> per-XCD working set = all of XT
// (8.5 MB) > 4 MB L2; panel re-reads stream from L3. With swz = (blk&7)*48 +
// blk>>3 (bijective, 384 = 8*48), each XCD's 48 blocks cover ~one pair's
// panels (~4 MB) -> L2-resident. Everything else byte-identical to R5.
__global__ __launch_bounds__(512) void gram_v10_kernel(
        const unsigned short* __restrict__ XT, const float* __restrict__ sums_p,
        float* __restrict__ part) {
    __shared__ __align__(16) unsigned short smem[2 * 64 * 256];   // 65536 B
    char* base = (char*)smem;

    int blk = blockIdx.x;                   // 0..383
    int swz = (blk & 7) * 48 + (blk >> 3);  // XCD-bijective: 384 = 8*48
    int p = swz >> 6;
    int tile = swz & 63;
    int a0 = (tile >> 3) * 32;
    int b0 = (tile & 7) * 32;
    int pi = pair_i(p), pj = pair_j(p);
    const unsigned short* Xp = XT + (size_t)pi * DIM * PITCH;
    const unsigned short* Yp = XT + (size_t)pj * DIM * PITCH;

    int tid = threadIdx.x;
    int w = tid >> 6;                // wave 0..7 -> k-slice within each chunk
    int L = tid & 63;

    int srow = tid >> 5;                       // 0..15
    int soffb = (tid & 31) * 16;               // byte offset in 512-B segment
    int swzb = soffb ^ ((srow & 7) << 4);      // (16+srow)&7 == srow&7
    const unsigned short* gA0 = Xp + (size_t)(a0 + srow) * PITCH + (swzb >> 1);
    const unsigned short* gA1 = Xp + (size_t)(a0 + 16 + srow) * PITCH + (swzb >> 1);
    const unsigned short* gB0 = Yp + (size_t)(b0 + srow) * PITCH + (swzb >> 1);
    const unsigned short* gB1 = Yp + (size_t)(b0 + 16 + srow) * PITCH + (swzb >> 1);
    int lp0 = tid * 16;
    int lp1 = 8192 + tid * 16;

    int rA = L & 15;
    int koffb = w * 64 + (L >> 4) * 16;
    int fr0 = rA * 512 + (koffb ^ ((rA & 7) << 4));

    f32x4 acc[2][2] = {};

    glds16(gA0, base + lp0);
    glds16(gA1, base + lp1);
    glds16(gB0, base + 16384 + lp0);
    glds16(gB1, base + 16384 + lp1);
    __syncthreads();

    for (int c = 0; c < 16; ++c) {
        if (c < 15) {
            int cn = (c + 1) * BK;
            char* Ab = base + ((c + 1) & 1) * 32768;
            glds16(gA0 + cn, Ab + lp0);
            glds16(gA1 + cn, Ab + lp1);
            glds16(gB0 + cn, Ab + 16384 + lp0);
            glds16(gB1 + cn, Ab + 16384 + lp1);
        }
        const char* Ar = base + (c & 1) * 32768;
        bf16x8 a0f = *(const bf16x8*)(Ar + fr0);
        bf16x8 a1f = *(const bf16x8*)(Ar + 8192 + fr0);
        bf16x8 b0f = *(const bf16x8*)(Ar + 16384 + fr0);
        bf16x8 b1f = *(const bf16x8*)(Ar + 16384 + 8192 + fr0);
        acc[0][0] = __builtin_amdgcn_mfma_f32_16x16x32_bf16(a0f, b0f, acc[0][0], 0, 0, 0);
        acc[0][1] = __builtin_amdgcn_mfma_f32_16x16x32_bf16(a0f, b1f, acc[0][1], 0, 0, 0);
        acc[1][0] = __builtin_amdgcn_mfma_f32_16x16x32_bf16(a1f, b0f, acc[1][0], 0, 0, 0);
        acc[1][1] = __builtin_amdgcn_mfma_f32_16x16x32_bf16(a1f, b1f, acc[1][1], 0, 0, 0);
        __syncthreads();
    }

    float* red  = (float*)base;
    float* sA   = (float*)(base + 33792);
    float* sB   = (float*)(base + 33920);
    float* wsum = (float*)(base + 34048);

    // C/D layout: col = lane&15, row = (lane>>4)*4 + reg   [measured m89/m91]
    #pragma unroll
    for (int ti = 0; ti < 2; ++ti)
        #pragma unroll
        for (int tj = 0; tj < 2; ++tj)
            #pragma unroll
            for (int r = 0; r < 4; ++r) {
                int m = ti * 16 + (L >> 4) * 4 + r;
                int n = tj * 16 + (L & 15);
                red[w * 1056 + m * 33 + n] = acc[ti][tj][r];
            }

    {
        int fl = tid >> 4;
        int pr = tid & 15;
        float4 va = *(const float4*)&sums_p[((size_t)(pi * DIM + a0 + fl)) * 64 + pr * 4];
        float4 vb = *(const float4*)&sums_p[((size_t)(pj * DIM + b0 + fl)) * 64 + pr * 4];
        float sa = va.x + va.y + va.z + va.w;
        float sb = vb.x + vb.y + vb.z + vb.w;
        sa += __shfl_down(sa, 8, 16);
        sa += __shfl_down(sa, 4, 16);
        sa += __shfl_down(sa, 2, 16);
        sa += __shfl_down(sa, 1, 16);
        sb += __shfl_down(sb, 8, 16);
        sb += __shfl_down(sb, 4, 16);
        sb += __shfl_down(sb, 2, 16);
        sb += __shfl_down(sb, 1, 16);
        if (pr == 0) { sA[fl] = sa; sB[fl] = sb; }
    }
    __syncthreads();

    const float inv_b = 1.0f / (float)B_ROWS;
    float local = 0.f;
    #pragma unroll
    for (int q = 0; q < 2; ++q) {
        int pos = tid + q * 512;
        int m = pos >> 5, n = pos & 31;
        float s = 0.f;
        #pragma unroll
        for (int ww = 0; ww < 8; ++ww) s += red[ww * 1056 + m * 33 + n];
        float v = s - sA[m] * sB[n] * inv_b;
        local = fmaf(v, v, local);
    }
    #pragma unroll
    for (int off = 32; off > 0; off >>= 1) local += __shfl_down(local, off, 64);
    if (L == 0) wsum[w] = local;
    __syncthreads();
    if (tid == 0) {
        float s = 0.f;
        #pragma unroll
        for (int ww = 0; ww < 8; ++ww) s += wsum[ww];
        part[blk] = s;                   // plain store — no atomic, no zero-init
    }
}

// Kernel 3 (main path): reduce 384 block partials, scale, write scalar.
__global__ __launch_bounds__(512) void finalize384_kernel(
        const float* __restrict__ part, float* __restrict__ out) {
    int t = threadIdx.x;
    float local = (t < NPAIR * 64) ? part[t] : 0.f;
    #pragma unroll
    for (int off = 32; off > 0; off >>= 1) local += __shfl_down(local, off, 64);
    __shared__ float ws2[8];
    if ((t & 63) == 0) ws2[t >> 6] = local;
    __syncthreads();
    if (t == 0) {
        float s = 0.f;
        #pragma unroll
        for (int ww = 0; ww < 8; ++ww) s += ws2[ww];
        const float scale = 0.1f / (6.0f * 4095.0f * 4095.0f);
        out[0] = s * scale;
    }
}

// Fallback-path finalize (scalar accumulator).
__global__ void finalize_kernel(const float* __restrict__ acc, float* __restrict__ out) {
    if (threadIdx.x == 0) {
        const float scale = 0.1f / (6.0f * 4095.0f * 4095.0f);
        out[0] = acc[0] * scale;
    }
}

// ============================ FALLBACK (R3 passing fp32 path) ============================

__global__ void col_sums_kernel(const float* __restrict__ e0, const float* __restrict__ e1,
                                const float* __restrict__ e2, const float* __restrict__ e3,
                                float* __restrict__ sums) {
    int e = blockIdx.y;
    const float* X = sel(e0, e1, e2, e3, e);
    int c = threadIdx.x;
    int r0 = blockIdx.x * 128;
    float s = 0.f;
    #pragma unroll 4
    for (int r = r0; r < r0 + 128; ++r) s += X[r * DIM + c];
    atomicAdd(&sums[e * DIM + c], s);
}

__global__ __launch_bounds__(256) void gram_kernel(
        const float* __restrict__ e0, const float* __restrict__ e1,
        const float* __restrict__ e2, const float* __restrict__ e3,
        float* __restrict__ G) {
    int kc = blockIdx.x;
    int tile = blockIdx.y;
    int p = blockIdx.z;
    const float* X = sel(e0, e1, e2, e3, pair_i(p));
    const float* Y = sel(e0, e1, e2, e3, pair_j(p));
    int a0 = (tile >> 2) * 64;
    int b0 = (tile & 3) * 64;
    int k0 = kc * KCHUNK;
    __shared__ float As[16][64];
    __shared__ float Bs[16][64];
    int lid = threadIdx.x;
    int lr = lid >> 4;
    int lc = (lid & 15) << 2;
    int ty = lid >> 4;
    int tx = lid & 15;
    float acc[4][4] = {};
    for (int ks = 0; ks < KCHUNK; ks += 16) {
        int row = k0 + ks + lr;
        float4 av = *(const float4*)&X[row * DIM + a0 + lc];
        float4 bv = *(const float4*)&Y[row * DIM + b0 + lc];
        __syncthreads();
        *(float4*)&As[lr][lc] = av;
        *(float4*)&Bs[lr][lc] = bv;
        __syncthreads();
        #pragma unroll
        for (int k = 0; k < 16; ++k) {
            float a[4], b[4];
            *(float4*)a = *(const float4*)&As[k][ty * 4];
            *(float4*)b = *(const float4*)&Bs[k][tx * 4];
            #pragma unroll
            for (int i = 0; i < 4; ++i)
                #pragma unroll
                for (int j = 0; j < 4; ++j)
                    acc[i][j] = fmaf(a[i], b[j], acc[i][j]);
        }
    }
    float* Gp = G + p * (DIM * DIM);
    #pragma unroll
    for (int i = 0; i < 4; ++i)
        #pragma unroll
        for (int j = 0; j < 4; ++j)
            atomicAdd(&Gp[(a0 + ty * 4 + i) * DIM + (b0 + tx * 4 + j)], acc[i][j]);
}

__global__ void reduce_kernel(const float* __restrict__ G, const float* __restrict__ sums,
                              float* __restrict__ acc) {
    float local = 0.f;
    const int total = NPAIR * DIM * DIM;
    for (int idx = blockIdx.x * blockDim.x + threadIdx.x; idx < total;
         idx += gridDim.x * blockDim.x) {
        int p = idx >> 16;
        int ab = idx & 65535;
        int a = ab >> 8;
        int b = ab & 255;
        float v = G[idx] - sums[pair_i(p) * DIM + a] * sums[pair_j(p) * DIM + b] * (1.0f / (float)B_ROWS);
        local = fmaf(v, v, local);
    }
    #pragma unroll
    for (int off = 32; off > 0; off >>= 1) local += __shfl_down(local, off, 64);
    __shared__ float wsum[4];
    if ((threadIdx.x & 63) == 0) wsum[threadIdx.x >> 6] = local;
    __syncthreads();
    if (threadIdx.x == 0) {
        float s = wsum[0] + wsum[1] + wsum[2] + wsum[3];
        atomicAdd(acc, s);
    }
}

// ============================ LAUNCH ============================

extern "C" void kernel_launch(void* const* d_in, const int* in_sizes, int n_in,
                              void* d_out, int out_size, void* d_ws, size_t ws_size,
                              hipStream_t stream) {
    const float* e0 = (const float*)d_in[0];
    const float* e1 = (const float*)d_in[1];
    const float* e2 = (const float*)d_in[2];
    const float* e3 = (const float*)d_in[3];

    // Main-path workspace layout (no zero-init required anywhere):
    //   sums_p : 4*256*64 f32 = 256 KB   @ 0
    //   part   : 384 f32                 @ 262144
    //   XT     : 4*256*4160 bf16 ~8.5 MB @ 266240
    size_t need = 266240 + (size_t)4 * DIM * PITCH * sizeof(unsigned short);

    if (ws_size >= need) {
        float* sums_p = (float*)d_ws;
        float* part = (float*)((char*)d_ws + 262144);
        unsigned short* XT = (unsigned short*)((char*)d_ws + 266240);
        transpose_bf16_kernel<<<dim3(64, 4, 4), 256, 0, stream>>>(e0, e1, e2, e3, XT, sums_p);
        gram_v10_kernel<<<NPAIR * 64, 512, 0, stream>>>(XT, sums_p, part);
        finalize384_kernel<<<1, 512, 0, stream>>>(part, (float*)d_out);
    } else {
        // fallback: fp32 vector path (passed in R3)
        float* sums = (float*)d_ws;                            // 4*256 f32 = 4 KB
        float* acc  = (float*)((char*)d_ws + 4096);            // 1 f32
        float* G = (float*)((char*)d_ws + 8192);
        size_t zbytes = 8192 + (size_t)NPAIR * DIM * DIM * sizeof(float);
        hipMemsetAsync(d_ws, 0, zbytes, stream);
        col_sums_kernel<<<dim3(32, 4), 256, 0, stream>>>(e0, e1, e2, e3, sums);
        gram_kernel<<<dim3(KSPLIT, 16, NPAIR), 256, 0, stream>>>(e0, e1, e2, e3, G);
        reduce_kernel<<<384, 256, 0, stream>>>(G, sums, acc);
        finalize_kernel<<<1, 64, 0, stream>>>(acc, (float*)d_out);
    }
}